// Round 5
// baseline (629.151 us; speedup 1.0000x reference)
//
#include <hip/hip_runtime.h>

typedef __bf16 bf16_t;
typedef __bf16 bf16x8 __attribute__((ext_vector_type(8)));
typedef float  f32x4  __attribute__((ext_vector_type(4)));
typedef unsigned int u32x4 __attribute__((ext_vector_type(4)));

#define T_STEPS 512
#define BATCH   2048
#define NS      64
#define FSTR    36
#define NSLOT   8      // x LDS ring slots (4 KB each)
#define DPF     6      // prefetch distance in steps (vmcnt(4) => 2 steps margin)

#define K_SIG  (-1.4426950408889634f)   // sigmoid: s = rcp(1+exp2(K_SIG*pre))
#define K_TANH ( 2.8853900817779268f)   // tanh:    t = 1-2*rcp(1+exp2(K_TANH*pre))

#define MFMA(A, B, C) __builtin_amdgcn_mfma_f32_16x16x32_bf16((A), (B), (C), 0, 0, 0)
#define RCPE(xv) __builtin_amdgcn_rcpf(1.0f + __builtin_amdgcn_exp2f(xv))

// lgkm-only barrier: in-flight global_load_lds DMAs cross it untouched
__device__ __forceinline__ void barrier_lgkm() {
  asm volatile("s_waitcnt lgkmcnt(0)\n\ts_barrier" ::: "memory");
}

// async global->LDS, 16B/lane, HW dest = lds_base + lane*16 (wave-uniform base)
__device__ __forceinline__ void async_load16(const float* g, char* l) {
  __builtin_amdgcn_global_load_lds(
      (const __attribute__((address_space(1))) void*)g,
      (__attribute__((address_space(3))) void*)l, 16, 0, 0);
}

// 4-wave cooperative LSTM chain: 16 batch rows x 32 hidden units per block.
// x is staged through an 8-slot LDS ring via global_load_lds (no VGPR ring ->
// no register-pressure-induced vmcnt exposure of HBM latency); each wave DMAs
// one 1KB quarter per step, prefetch distance 6, counted s_waitcnt vmcnt(4).
// LDS x tile is XOR-swizzled (pre-swizzled GLOBAL source, linear LDS dest;
// same XOR on ds_read) so the 4 ds_read_b128/lane are bank-conflict-free.
// Waves split activations (trans pipe) 4 ways; h re-broadcast via packed-u32
// LDS exchange, double-buffered, one barrier/step. W_hh contraction order is
// permuted so MFMA C/D h-layout == next step's B-frag layout.
__global__ __launch_bounds__(256, 1)
void lstm_policy_kernel(const float* __restrict__ x,
                        const float* __restrict__ W_ih,
                        const float* __restrict__ W_hh,
                        const float* __restrict__ b_ih,
                        const float* __restrict__ b_hh,
                        const float* __restrict__ W_d,
                        const float* __restrict__ b_d,
                        float* __restrict__ out)
{
  __shared__ char  xlds[NSLOT * 4096];     // x ring: slot = [16 rows][64 f32] swz
  __shared__ unsigned int hlds[2][4][64];  // [parity][wave][lane] packed 2xbf16
  __shared__ float hf[16 * FSTR];          // final relu(h) for dense epilogue

  const int tid  = threadIdx.x;
  const int wv   = tid >> 6;               // 0..3
  const int lane = tid & 63;
  const int m    = lane & 15;              // batch row within tile (B-col)
  const int q    = lane >> 4;              // 0..3
  const int U    = wv >> 1;                // this wave's unit-tile (0 or 1)
  const int rsel = wv & 1;                 // 0: cells r=0,1   1: cells r=2,3
  const int row0 = blockIdx.x << 4;        // global batch row base

  // ---- preload W frags for our U, pre-scaled by activation input constants ----
  bf16x8 a_ih[4][2], a_hh[4];
  f32x4  bias[4];
  #pragma unroll
  for (int G = 0; G < 4; ++G) {
    const float k = (G == 2) ? K_TANH : K_SIG;
    const int wrow = (G << 5) + (U << 4) + m;      // gate-major row of 4H=128
    const float* pih = W_ih + wrow * 64;
    const float* phh = W_hh + (wrow << 5);
    #pragma unroll
    for (int j = 0; j < 8; ++j) {
      a_ih[G][0][j] = (bf16_t)(k * pih[(q << 3) + j]);
      a_ih[G][1][j] = (bf16_t)(k * pih[32 + (q << 3) + j]);
      const int us = (j < 4) ? ((q << 2) + j) : (16 + (q << 2) + (j - 4));
      a_hh[G][j] = (bf16_t)(k * phh[us]);          // permuted contraction order
    }
    #pragma unroll
    for (int r = 0; r < 4; ++r) {
      const int u = (G << 5) + (U << 4) + (q << 2) + r;
      bias[G][r] = (b_ih[u] + b_hh[u]) * k;
    }
  }

  const size_t xstep = (size_t)BATCH * NS;         // 1<<17 floats per timestep
  const float* xb = x + (size_t)row0 * NS;         // our 16x64 tile is contiguous

  // staging source: lane's 16B chunk, inverse-swizzled (loop-invariant)
  const int slin = (wv << 10) + (lane << 4);       // linear byte within 4KB tile
  const int ssrc = slin ^ (((slin >> 8) & 7) << 4);
  const float* gsrc = xb + (ssrc >> 2);
  char* const lqbase = xlds + (wv << 10);          // our quarter's LDS base

  // read offsets: lane (m,q) wants tile bytes m*256+q*32 +{0,16,128,144}, swz'd
  const int rb  = m * 256 + (q << 5);
  const int sw  = (m & 7) << 4;
  const int ro0 = rb ^ sw;
  const int ro1 = (rb + 16) ^ sw;
  const int ro2 = (rb + 128) ^ sw;
  const int ro3 = (rb + 144) ^ sw;

  // ---- prologue: stage x[0..5]; loads 0,1 guaranteed by vmcnt(4) ----
  #pragma unroll
  for (int s = 0; s < DPF; ++s)
    async_load16(gsrc + (size_t)s * xstep, lqbase + (s << 12));
  asm volatile("s_waitcnt vmcnt(4)" ::: "memory");
  __syncthreads();

  // ---- acc[G]: gate pre-activations for t=0 from LDS slot 0 ----
  f32x4 acc[4];
  {
    const char* sp = xlds;                         // slot 0
    const f32x4 xr0 = *(const f32x4*)(sp + ro0);
    const f32x4 xr1 = *(const f32x4*)(sp + ro1);
    const f32x4 xr2 = *(const f32x4*)(sp + ro2);
    const f32x4 xr3 = *(const f32x4*)(sp + ro3);
    bf16x8 xA, xB;
    #pragma unroll
    for (int j = 0; j < 4; ++j) {
      xA[j] = (bf16_t)xr0[j]; xA[4+j] = (bf16_t)xr1[j];
      xB[j] = (bf16_t)xr2[j]; xB[4+j] = (bf16_t)xr3[j];
    }
    #pragma unroll
    for (int G = 0; G < 4; ++G) {
      acc[G] = MFMA(a_ih[G][0], xA, bias[G]);
      acc[G] = MFMA(a_ih[G][1], xB, acc[G]);
    }
  }

  float cst[2] = {0.0f, 0.0f};   // c-state for our 2 cells (K_TANH-scaled basis)
  bf16x8 hB = {};                // full h B-frag (h_{-1}=0), rebuilt each step

  // one cell's activation math (literal RR index)
  #define CELL(RR, E, HOUT)                                                         \
    {                                                                               \
      const float iv = RCPE(gr[0][RR]);                                             \
      const float fv = RCPE(gr[1][RR]);                                             \
      const float rg = RCPE(gr[2][RR]);                                             \
      const float ov = RCPE(gr[3][RR]);                                             \
      const float gs = __builtin_fmaf(-2.0f * K_TANH, rg, K_TANH);  /* K*tanh(g) */ \
      const float cn = __builtin_fmaf(fv, cst[E], iv * gs);         /* K*c_new  */  \
      cst[E] = cn;                                                                  \
      const float rh  = RCPE(cn);                                                   \
      const float ov2 = ov + ov;                                                    \
      HOUT = __builtin_fmaf(-ov2, rh, ov);                          /* o*tanh(c) */ \
      if (tt == T_STEPS - 1) hf[m * FSTR + (U << 4) + (q << 2) + RR] = fmaxf(HOUT, 0.0f); \
    }

  // STEP(P): early x-read(t+1) -> h-MFMA -> act -> h write -> DMA(t+6) ->
  //          vmcnt(4) -> barrier -> h-reads ; x-MFMAs fill read latency -> hB.
  #define STEP(P)                                                                   \
  do {                                                                              \
    const int tt  = t + (P);                                                        \
    const int par = (P) & 1;                                                        \
    /* 1. x[t+1] from ring (slot ready per prev step's vmcnt+barrier) */            \
    const char* sp = xlds + (((tt + 1) & 7) << 12);                                 \
    const f32x4 xr0 = *(const f32x4*)(sp + ro0);                                    \
    const f32x4 xr1 = *(const f32x4*)(sp + ro1);                                    \
    const f32x4 xr2 = *(const f32x4*)(sp + ro2);                                    \
    const f32x4 xr3 = *(const f32x4*)(sp + ro3);                                    \
    /* 2. h-part MFMAs */                                                           \
    f32x4 gr[4];                                                                    \
    _Pragma("unroll")                                                               \
    for (int G = 0; G < 4; ++G)                                                     \
      gr[G] = MFMA(a_hh[G], hB, acc[G]);                                            \
    /* 3. activations (2 cells) + packed h publish */                               \
    float h0, h1;                                                                   \
    if (rsel == 0) { CELL(0, 0, h0) CELL(1, 1, h1) }                                \
    else           { CELL(2, 0, h0) CELL(3, 1, h1) }                                \
    {                                                                               \
      const unsigned int s0 = __builtin_bit_cast(unsigned short, (bf16_t)h0);       \
      const unsigned int s1 = __builtin_bit_cast(unsigned short, (bf16_t)h1);       \
      hlds[par][wv][lane] = s0 | (s1 << 16);                                        \
    }                                                                               \
    /* 4. DMA prefetch x[tt+6] (always issue: vmcnt accounting stays exact) */      \
    {                                                                               \
      int tp = tt + DPF; if (tp > T_STEPS - 1) tp = T_STEPS - 1;                    \
      async_load16(gsrc + (size_t)tp * xstep, lqbase + ((tp & 7) << 12));           \
    }                                                                               \
    /* 5. counted wait + exchange barrier */                                        \
    asm volatile("s_waitcnt vmcnt(4)" ::: "memory");                                \
    barrier_lgkm();                                                                 \
    /* 6. h exchange reads (latency hidden by 7) */                                 \
    const unsigned int w0 = hlds[par][0][lane];                                     \
    const unsigned int w1 = hlds[par][1][lane];                                     \
    const unsigned int w2 = hlds[par][2][lane];                                     \
    const unsigned int w3 = hlds[par][3][lane];                                     \
    /* 7. x-part for t+1 overwrites acc (WAR) */                                    \
    {                                                                               \
      bf16x8 xA, xB;                                                                \
      _Pragma("unroll")                                                             \
      for (int j = 0; j < 4; ++j) {                                                 \
        xA[j] = (bf16_t)xr0[j]; xA[4+j] = (bf16_t)xr1[j];                           \
        xB[j] = (bf16_t)xr2[j]; xB[4+j] = (bf16_t)xr3[j];                           \
      }                                                                             \
      _Pragma("unroll")                                                             \
      for (int G = 0; G < 4; ++G) {                                                 \
        acc[G] = MFMA(a_ih[G][0], xA, bias[G]);                                     \
        acc[G] = MFMA(a_ih[G][1], xB, acc[G]);                                      \
      }                                                                             \
    }                                                                               \
    /* 8. assemble next hB */                                                       \
    {                                                                               \
      u32x4 hw; hw[0] = w0; hw[1] = w1; hw[2] = w2; hw[3] = w3;                     \
      hB = __builtin_bit_cast(bf16x8, hw);                                          \
    }                                                                               \
  } while (0)

  #pragma unroll 1
  for (int t = 0; t < T_STEPS; t += 4) {
    STEP(0);
    STEP(1);
    STEP(2);
    STEP(3);
  }
  #undef STEP
  #undef CELL

  __syncthreads();

  // dense epilogue: out[row][a] = relu(h_T[row]) . W_d[a] + b_d[a]
  if (tid < 48) {
    const int r = tid / 3;
    const int a = tid - r * 3;
    float s = b_d[a];
    #pragma unroll
    for (int u = 0; u < 32; ++u)
      s += hf[r * FSTR + u] * W_d[a * 32 + u];
    out[(size_t)(row0 + r) * 3 + a] = s;
  }
}

extern "C" void kernel_launch(void* const* d_in, const int* in_sizes, int n_in,
                              void* d_out, int out_size, void* d_ws, size_t ws_size,
                              hipStream_t stream) {
  const float* x    = (const float*)d_in[0];
  const float* W_ih = (const float*)d_in[1];
  const float* W_hh = (const float*)d_in[2];
  const float* b_ih = (const float*)d_in[3];
  const float* b_hh = (const float*)d_in[4];
  const float* W_d  = (const float*)d_in[5];
  const float* b_d  = (const float*)d_in[6];
  float* out = (float*)d_out;

  dim3 grid(BATCH / 16);   // 128 chains, one per block
  dim3 block(256);         // 4 waves: trans split + 4x 1KB DMA quarters
  hipLaunchKernelGGL(lstm_policy_kernel, grid, block, 0, stream,
                     x, W_ih, W_hh, b_ih, b_hh, W_d, b_d, out);
}